// Round 9
// baseline (112.801 us; speedup 1.0000x reference)
//
#include <hip/hip_runtime.h>
#include <math.h>

// Problem constants (fixed by setup_inputs)
#define NN   256   // N rows
#define CCH  512   // C features
#define MMM  64    // M slices
#define KPOS 8     // K positives
#define MARG 0.2f

typedef _Float16 f16x8 __attribute__((ext_vector_type(8)));
typedef float    f32x4 __attribute__((ext_vector_type(4)));

// Packed fragment layout (MFMA A and B operands read the same pattern):
// P[m][rb][cb][lane] : lane l holds X[m][rb*16 + (l&15)][cb*32 + (l>>4)*8 + j]
#define FRAG(m, rb, cb) ((((size_t)(m) * 16 + (rb)) * 16 + (cb)) * 64)

// Workspace layout (bytes). Single fp16 copy (round-7: single-pass fp16 is
// exact-distances-of-rounded-points; error ~2e-4 << 2.1e-2 threshold).
#define PH_OFF   ((size_t)0)
#define PH_BYTES ((size_t)MMM * 16 * 16 * 64 * 16)   // 16,777,216
#define X2_OFF   (PH_OFF + PH_BYTES)
#define DAP_OFF  (X2_OFF + (size_t)MMM * NN * 4)
#define POS_OFF  (DAP_OFF + (size_t)MMM * NN * KPOS * 4)
#define NEG_OFF  (POS_OFF + (size_t)NN * KPOS * 4)
#define S_OFF    (NEG_OFF + (size_t)NN * 4 * 8)
#define CNT_OFF  (S_OFF + (size_t)MMM * 4)
#define DONE_OFF (CNT_OFF + (size_t)MMM * 4)

// ---------------------------------------------------------------------------
// Kernel TH: fused transpose + fp16 convert + fragment packing.
// Block 1024 runs the kP logic via ballots and zeroes accumulators + done.
// ---------------------------------------------------------------------------
__global__ __launch_bounds__(256) void kTH(const float* __restrict__ f,
                                           f16x8* __restrict__ Ph,
                                           const int* __restrict__ label,
                                           int* __restrict__ pos_idx,
                                           unsigned long long* __restrict__ neg_mask,
                                           float* __restrict__ s_acc,
                                           unsigned int* __restrict__ c_acc,
                                           unsigned int* __restrict__ done) {
  __shared__ unsigned int S[512 * 20];   // 40 KB
  int bid = blockIdx.x;
  int t = threadIdx.x;

  if (bid >= 1024) {                     // ---- kP body (ballot version) ----
    unsigned long long* cm = (unsigned long long*)S;   // [32 classes][4 words]
    if (t < MMM) { s_acc[t] = 0.0f; c_acc[t] = 0u; }
    if (t == 0) *done = 0u;
    int lab = label[t];                  // t == k, 256 threads == NN
    int wv = t >> 6;
    #pragma unroll 1
    for (int c = 0; c < 32; ++c) {
      unsigned long long b = __ballot(lab == c);
      if ((t & 63) == 0) cm[c * 4 + wv] = b;
    }
    __syncthreads();
    int n = t;
    unsigned long long pm0 = cm[lab*4+0], pm1 = cm[lab*4+1],
                       pm2 = cm[lab*4+2], pm3 = cm[lab*4+3];
    const unsigned long long P0 = pm0, P1 = pm1, P2 = pm2, P3 = pm3;
    unsigned long long e0 = 0, e1 = 0, e2 = 0, e3 = 0;
    #pragma unroll
    for (int r = 0; r < 8; ++r) {        // first 8 of stable order (pos then neg)
      unsigned long long q0 = pm0, q1 = pm1, q2 = pm2, q3 = pm3;
      if (!(pm0 | pm1 | pm2 | pm3)) {    // P<8 fallback: promote negatives
        q0 = ~(P0 | e0); q1 = ~(P1 | e1); q2 = ~(P2 | e2); q3 = ~(P3 | e3);
      }
      int k;
      if (q0) k = __builtin_ctzll(q0);
      else if (q1) k = 64 + __builtin_ctzll(q1);
      else if (q2) k = 128 + __builtin_ctzll(q2);
      else if (q3) k = 192 + __builtin_ctzll(q3);
      else k = 0;
      pos_idx[n * KPOS + r] = k;
      unsigned long long b = 1ull << (k & 63);
      if (k < 64)       { pm0 &= ~b; e0 |= b; }
      else if (k < 128) { pm1 &= ~b; e1 |= b; }
      else if (k < 192) { pm2 &= ~b; e2 |= b; }
      else              { pm3 &= ~b; e3 |= b; }
    }
    neg_mask[n*4+0] = ~e0; neg_mask[n*4+1] = ~e1;
    neg_mask[n*4+2] = ~e2; neg_mask[n*4+3] = ~e3;
    return;
  }

  int rb = bid >> 6, cb = (bid >> 2) & 15, mq = bid & 3;
  // read phase: 512 (n,c) pairs x 16 m; each thread: 8 float4 loads
  int s = t & 3, pg = t >> 2;
  #pragma unroll
  for (int it = 0; it < 8; ++it) {
    int p = it * 64 + pg;               // 0..511
    int n_loc = p & 15, c_loc = p >> 4;
    const float4 v4 = *(const float4*)&f[((size_t)(rb * 16 + n_loc) * CCH
                                          + (cb * 32 + c_loc)) * MMM + mq * 16 + s * 4];
    uint4 pk;
    pk.x = (unsigned int)__builtin_bit_cast(unsigned short, (_Float16)v4.x);
    pk.y = (unsigned int)__builtin_bit_cast(unsigned short, (_Float16)v4.y);
    pk.z = (unsigned int)__builtin_bit_cast(unsigned short, (_Float16)v4.z);
    pk.w = (unsigned int)__builtin_bit_cast(unsigned short, (_Float16)v4.w);
    *(uint4*)&S[p * 20 + s * 4] = pk;   // 16B-aligned
  }
  __syncthreads();
  // write phase: 16 m_loc x 64 lanes fragments, coalesced 16B stores
  #pragma unroll
  for (int it = 0; it < 4; ++it) {
    int e = it * 256 + t;
    int m_loc = e >> 6, l = e & 63;
    int m = mq * 16 + m_loc;
    f16x8 vh;
    #pragma unroll
    for (int j = 0; j < 8; ++j) {
      unsigned int w = S[(((l >> 4) * 8 + j) * 16 + (l & 15)) * 20 + m_loc];
      vh[j] = __builtin_bit_cast(_Float16, (unsigned short)(w & 0xffffu));
    }
    Ph[FRAG(m, rb, cb) + l] = vh;
  }
}

// ---------------------------------------------------------------------------
// Kernel A2: per (m, class) 8x8 exact distances of the ROUNDED points.
// Self-distance exactly 0 structurally (diag uses the same D8 value twice).
// ---------------------------------------------------------------------------
__global__ __launch_bounds__(256) void kA2(const f16x8* __restrict__ Ph,
                                           const int* __restrict__ pos_idx,
                                           float* __restrict__ x2,
                                           float* __restrict__ dap) {
  __shared__ float R[8][520];
  __shared__ float D8[64];
  int bid = blockIdx.x;
  int m = bid & 63, cl = bid >> 6;
  int t = threadIdx.x;
  #pragma unroll
  for (int half = 0; half < 2; ++half) {
    int e = half * 256 + t;
    int i = e >> 6, le = e & 63, cbb = le >> 2, g = le & 3;
    int mi = pos_idx[cl * 8 + i];
    f16x8 vh = Ph[FRAG(m, mi >> 4, cbb) + (g * 16 + (mi & 15))];
    #pragma unroll
    for (int j = 0; j < 8; ++j)
      R[i][cbb * 32 + g * 8 + j] = (float)vh[j];
  }
  __syncthreads();
  {
    int d = t >> 2, q = t & 3, i = d >> 3, i2 = d & 7;
    const float4* Ri4 = (const float4*)(&R[i][q * 128]);
    const float4* Rj4 = (const float4*)(&R[i2][q * 128]);
    float p = 0.0f;
    #pragma unroll
    for (int c = 0; c < 32; ++c) {
      float4 a = Ri4[c], b = Rj4[c];
      p += a.x * b.x + a.y * b.y + a.z * b.z + a.w * b.w;
    }
    p += __shfl_down(p, 2, 4);
    p += __shfl_down(p, 1, 4);
    if (q == 0) D8[d] = p;
  }
  __syncthreads();
  if (t < 64) {
    int ii = t >> 3, jj = t & 7;
    float x2a = D8[ii * 8 + ii], x2b = D8[jj * 8 + jj];
    float z = x2a + x2b - 2.0f * D8[t];
    float dist = (z > 0.0f) ? sqrtf(z) : 0.0f;
    int mi = pos_idx[cl * 8 + ii];
    dap[((size_t)m * NN + mi) * KPOS + jj] = dist;
    if (ii == jj) x2[m * NN + mi] = x2a;
  }
}

// ---------------------------------------------------------------------------
// Kernel B v3: barrier-free, LDS-free. 4096 one-wave blocks, 32x32 tile each,
// 3-deep register prefetch, fully unrolled (static array indices only).
// Theory: rounds 4-7's invariant ~50-60us was the per-chunk __syncthreads
// vmcnt(0) convoy; independent waves + TLP remove it entirely.
// ---------------------------------------------------------------------------
#define MFMA16(d, a, b) d = __builtin_amdgcn_mfma_f32_16x16x32_f16(a, b, d, 0, 0, 0)

__global__ __launch_bounds__(64, 4) void kB(
    const f16x8* __restrict__ Ph,
    const float* __restrict__ x2, const float* __restrict__ dap,
    const unsigned long long* __restrict__ neg_mask,
    float* __restrict__ s_acc, unsigned int* __restrict__ c_acc,
    unsigned int* __restrict__ done, float* __restrict__ out) {
  int bid = blockIdx.x;                 // 4096 blocks
  int m = bid & 63;                     // XCD-aligned: m%8 == bid%8
  int sub = bid >> 6;                   // 0..63
  int kb = sub >> 3, nb = sub & 7;      // 32-row k block, 32-col n block
  int lane = threadIdx.x;               // one wave per block

  const f16x8* PA0 = Ph + FRAG(m, kb * 2 + 0, 0) + lane;
  const f16x8* PA1 = Ph + FRAG(m, kb * 2 + 1, 0) + lane;
  const f16x8* PB0 = Ph + FRAG(m, nb * 2 + 0, 0) + lane;
  const f16x8* PB1 = Ph + FRAG(m, nb * 2 + 1, 0) + lane;
  // cb stride within a row-block = 64 f16x8

  f32x4 acc[2][2];
  acc[0][0] = (f32x4){0.f,0.f,0.f,0.f}; acc[0][1] = (f32x4){0.f,0.f,0.f,0.f};
  acc[1][0] = (f32x4){0.f,0.f,0.f,0.f}; acc[1][1] = (f32x4){0.f,0.f,0.f,0.f};

  f16x8 a0[3], a1[3], b0[3], b1[3];
  #define LOADC(slot, c) { a0[slot] = PA0[(c) * 64]; a1[slot] = PA1[(c) * 64]; \
                           b0[slot] = PB0[(c) * 64]; b1[slot] = PB1[(c) * 64]; }
  LOADC(0, 0) LOADC(1, 1) LOADC(2, 2)
  #pragma unroll
  for (int i = 0; i < 16; ++i) {        // full unroll -> i%3 is static
    int s = i % 3;
    MFMA16(acc[0][0], a0[s], b0[s]); MFMA16(acc[0][1], a0[s], b1[s]);
    MFMA16(acc[1][0], a1[s], b0[s]); MFMA16(acc[1][1], a1[s], b1[s]);
    if (i + 3 < 16) LOADC(s, i + 3)
  }

  // Epilogue. D frag: col = lane&15 (n), row = (lane>>4)*4 + reg (k).
  int col = lane & 15, rq = lane >> 4;
  int n0 = nb * 32 + col;
  int n1 = n0 + 16;
  float x2n0 = x2[m * NN + n0], x2n1 = x2[m * NN + n1];
  float dv0[8], dv1[8];
  {
    const float4* dp0 = (const float4*)&dap[((size_t)m * NN + n0) * KPOS];
    const float4* dp1 = (const float4*)&dap[((size_t)m * NN + n1) * KPOS];
    float4 w0 = dp0[0], w1 = dp0[1], w2 = dp1[0], w3 = dp1[1];
    dv0[0]=w0.x; dv0[1]=w0.y; dv0[2]=w0.z; dv0[3]=w0.w;
    dv0[4]=w1.x; dv0[5]=w1.y; dv0[6]=w1.z; dv0[7]=w1.w;
    dv1[0]=w2.x; dv1[1]=w2.y; dv1[2]=w2.z; dv1[3]=w2.w;
    dv1[4]=w3.x; dv1[5]=w3.y; dv1[6]=w3.z; dv1[7]=w3.w;
  }
  int kw = kb >> 1;                     // k>>6, uniform per block
  unsigned long long nmw0 = neg_mask[n0 * 4 + kw];
  unsigned long long nmw1 = neg_mask[n1 * 4 + kw];

  float ls = 0.0f; unsigned int lc = 0u;
  #pragma unroll
  for (int i = 0; i < 2; ++i) {
    #pragma unroll
    for (int reg = 0; reg < 4; ++reg) {
      int klo = i * 16 + rq * 4 + reg;             // k & 31
      int k = kb * 32 + klo;
      int kbit = k & 63;
      float x2k = x2[m * NN + k];
      {
        float z = x2n0 + x2k - 2.0f * acc[i][0][reg];
        float dist = (z > 0.0f) ? sqrtf(z) : 0.0f;
        if ((nmw0 >> kbit) & 1ull) {
          #pragma unroll
          for (int p = 0; p < 8; ++p) {
            float tt = MARG + dv0[p] - dist;
            if (tt > 0.0f) { ls += tt; lc++; }
          }
        }
      }
      {
        float z = x2n1 + x2k - 2.0f * acc[i][1][reg];
        float dist = (z > 0.0f) ? sqrtf(z) : 0.0f;
        if ((nmw1 >> kbit) & 1ull) {
          #pragma unroll
          for (int p = 0; p < 8; ++p) {
            float tt = MARG + dv1[p] - dist;
            if (tt > 0.0f) { ls += tt; lc++; }
          }
        }
      }
    }
  }
  #pragma unroll
  for (int off = 32; off > 0; off >>= 1) {
    ls += __shfl_down(ls, off, 64);
    lc += __shfl_down(lc, off, 64);
  }
  int fl = 0;
  if (lane == 0) {
    atomicAdd(&s_acc[m], ls);
    atomicAdd(&c_acc[m], lc);
    __threadfence();
    unsigned int prev = atomicAdd(done, 1u);
    fl = (prev == 4095u) ? 1 : 0;
  }
  fl = __shfl(fl, 0, 64);
  if (fl) {                             // last block finalizes (fold of kC)
    __threadfence();
    float c  = (float)c_acc[lane];
    float sm = s_acc[lane];
    float mean = (c > 0.0f) ? (sm / c) : 0.0f;
    float csum = c;
    #pragma unroll
    for (int off = 32; off > 0; off >>= 1) {
      mean += __shfl_down(mean, off, 64);
      csum += __shfl_down(csum, off, 64);
    }
    if (lane == 0) {
      out[0] = mean / 64.0f;
      // lm.size = M * N * K * (N-K) = 64*256*8*248 = 32,505,856
      out[1] = (csum / 64.0f) / 32505856.0f;
    }
  }
}

extern "C" void kernel_launch(void* const* d_in, const int* in_sizes, int n_in,
                              void* d_out, int out_size, void* d_ws, size_t ws_size,
                              hipStream_t stream) {
  const float* feature = (const float*)d_in[0];
  const int*   label   = (const int*)d_in[1];
  char* w = (char*)d_ws;
  f16x8* Ph = (f16x8*)(w + PH_OFF);
  float* x2  = (float*)(w + X2_OFF);
  float* dap = (float*)(w + DAP_OFF);
  int*   pos = (int*)(w + POS_OFF);
  unsigned long long* neg = (unsigned long long*)(w + NEG_OFF);
  float* s_acc = (float*)(w + S_OFF);
  unsigned int* c_acc = (unsigned int*)(w + CNT_OFF);
  unsigned int* done  = (unsigned int*)(w + DONE_OFF);
  float* out = (float*)d_out;

  kTH<<<1025, 256, 0, stream>>>(feature, Ph, label, pos, neg, s_acc, c_acc, done);
  kA2<<<2048, 256, 0, stream>>>(Ph, pos, x2, dap);
  kB <<<4096, 64,  0, stream>>>(Ph, x2, dap, neg, s_acc, c_acc, done, out);
}

// Round 10
// 59.502 us; speedup vs baseline: 1.8958x; 1.8958x over previous
//
#include <hip/hip_runtime.h>
#include <math.h>

// Problem constants (fixed by setup_inputs)
#define NN   256   // N rows
#define CCH  512   // C features
#define MMM  64    // M slices
#define KPOS 8     // K positives
#define MARG 0.2f

typedef _Float16 f16x8 __attribute__((ext_vector_type(8)));
typedef float    f32x4 __attribute__((ext_vector_type(4)));

// Packed fragment layout (MFMA A and B operands read the same pattern):
// P[m][rb][cb][lane] : lane l holds X[m][rb*16 + (l&15)][cb*32 + (l>>4)*8 + j]
#define FRAG(m, rb, cb) ((((size_t)(m) * 16 + (rb)) * 16 + (cb)) * 64)

// Workspace layout (bytes). Single fp16 copy (round-7: single-pass fp16 is
// exact-distances-of-rounded-points; error ~2e-4 << 2.1e-2 threshold).
#define PH_OFF   ((size_t)0)
#define PH_BYTES ((size_t)MMM * 16 * 16 * 64 * 16)   // 16,777,216
#define X2_OFF   (PH_OFF + PH_BYTES)
#define DAP_OFF  (X2_OFF + (size_t)MMM * NN * 4)
#define POS_OFF  (DAP_OFF + (size_t)MMM * NN * KPOS * 4)
#define NEG_OFF  (POS_OFF + (size_t)NN * KPOS * 4)
#define S_OFF    (NEG_OFF + (size_t)NN * 4 * 8)
#define CNT_OFF  (S_OFF + (size_t)MMM * 4)
#define DONE_OFF (CNT_OFF + (size_t)MMM * 4)

// async global->LDS, 16B per lane: LDS dest = wave-uniform base + lane*16
#define GLD_LDS16(gp, lp) __builtin_amdgcn_global_load_lds(                 \
    (const __attribute__((address_space(1))) void*)(gp),                    \
    (__attribute__((address_space(3))) void*)(lp), 16, 0, 0)

// ---------------------------------------------------------------------------
// Kernel TH: fused transpose + fp16 convert + fragment packing.
// Block 1024 runs the kP logic via ballots and zeroes accumulators + done.
// ---------------------------------------------------------------------------
__global__ __launch_bounds__(256) void kTH(const float* __restrict__ f,
                                           f16x8* __restrict__ Ph,
                                           const int* __restrict__ label,
                                           int* __restrict__ pos_idx,
                                           unsigned long long* __restrict__ neg_mask,
                                           float* __restrict__ s_acc,
                                           unsigned int* __restrict__ c_acc,
                                           unsigned int* __restrict__ done) {
  __shared__ unsigned int S[512 * 20];   // 40 KB
  int bid = blockIdx.x;
  int t = threadIdx.x;

  if (bid >= 1024) {                     // ---- kP body (ballot version) ----
    unsigned long long* cm = (unsigned long long*)S;   // [32 classes][4 words]
    if (t < MMM) { s_acc[t] = 0.0f; c_acc[t] = 0u; }
    if (t == 0) *done = 0u;
    int lab = label[t];                  // t == k, 256 threads == NN
    int wv = t >> 6;
    #pragma unroll 1
    for (int c = 0; c < 32; ++c) {
      unsigned long long b = __ballot(lab == c);
      if ((t & 63) == 0) cm[c * 4 + wv] = b;
    }
    __syncthreads();
    int n = t;
    unsigned long long pm0 = cm[lab*4+0], pm1 = cm[lab*4+1],
                       pm2 = cm[lab*4+2], pm3 = cm[lab*4+3];
    const unsigned long long P0 = pm0, P1 = pm1, P2 = pm2, P3 = pm3;
    unsigned long long e0 = 0, e1 = 0, e2 = 0, e3 = 0;
    #pragma unroll
    for (int r = 0; r < 8; ++r) {        // first 8 of stable order (pos then neg)
      unsigned long long q0 = pm0, q1 = pm1, q2 = pm2, q3 = pm3;
      if (!(pm0 | pm1 | pm2 | pm3)) {    // P<8 fallback: promote negatives
        q0 = ~(P0 | e0); q1 = ~(P1 | e1); q2 = ~(P2 | e2); q3 = ~(P3 | e3);
      }
      int k;
      if (q0) k = __builtin_ctzll(q0);
      else if (q1) k = 64 + __builtin_ctzll(q1);
      else if (q2) k = 128 + __builtin_ctzll(q2);
      else if (q3) k = 192 + __builtin_ctzll(q3);
      else k = 0;
      pos_idx[n * KPOS + r] = k;
      unsigned long long b = 1ull << (k & 63);
      if (k < 64)       { pm0 &= ~b; e0 |= b; }
      else if (k < 128) { pm1 &= ~b; e1 |= b; }
      else if (k < 192) { pm2 &= ~b; e2 |= b; }
      else              { pm3 &= ~b; e3 |= b; }
    }
    neg_mask[n*4+0] = ~e0; neg_mask[n*4+1] = ~e1;
    neg_mask[n*4+2] = ~e2; neg_mask[n*4+3] = ~e3;
    return;
  }

  int rb = bid >> 6, cb = (bid >> 2) & 15, mq = bid & 3;
  // read phase: 512 (n,c) pairs x 16 m; each thread: 8 float4 loads
  int s = t & 3, pg = t >> 2;
  #pragma unroll
  for (int it = 0; it < 8; ++it) {
    int p = it * 64 + pg;               // 0..511
    int n_loc = p & 15, c_loc = p >> 4;
    const float4 v4 = *(const float4*)&f[((size_t)(rb * 16 + n_loc) * CCH
                                          + (cb * 32 + c_loc)) * MMM + mq * 16 + s * 4];
    uint4 pk;
    pk.x = (unsigned int)__builtin_bit_cast(unsigned short, (_Float16)v4.x);
    pk.y = (unsigned int)__builtin_bit_cast(unsigned short, (_Float16)v4.y);
    pk.z = (unsigned int)__builtin_bit_cast(unsigned short, (_Float16)v4.z);
    pk.w = (unsigned int)__builtin_bit_cast(unsigned short, (_Float16)v4.w);
    *(uint4*)&S[p * 20 + s * 4] = pk;   // 16B-aligned
  }
  __syncthreads();
  // write phase: 16 m_loc x 64 lanes fragments, coalesced 16B stores
  #pragma unroll
  for (int it = 0; it < 4; ++it) {
    int e = it * 256 + t;
    int m_loc = e >> 6, l = e & 63;
    int m = mq * 16 + m_loc;
    f16x8 vh;
    #pragma unroll
    for (int j = 0; j < 8; ++j) {
      unsigned int w = S[(((l >> 4) * 8 + j) * 16 + (l & 15)) * 20 + m_loc];
      vh[j] = __builtin_bit_cast(_Float16, (unsigned short)(w & 0xffffu));
    }
    Ph[FRAG(m, rb, cb) + l] = vh;
  }
}

// ---------------------------------------------------------------------------
// Kernel A2: per (m, class) 8x8 exact distances of the ROUNDED points.
// Self-distance exactly 0 structurally (diag uses the same D8 value twice).
// ---------------------------------------------------------------------------
__global__ __launch_bounds__(256) void kA2(const f16x8* __restrict__ Ph,
                                           const int* __restrict__ pos_idx,
                                           float* __restrict__ x2,
                                           float* __restrict__ dap) {
  __shared__ float R[8][520];
  __shared__ float D8[64];
  int bid = blockIdx.x;
  int m = bid & 63, cl = bid >> 6;
  int t = threadIdx.x;
  #pragma unroll
  for (int half = 0; half < 2; ++half) {
    int e = half * 256 + t;
    int i = e >> 6, le = e & 63, cbb = le >> 2, g = le & 3;
    int mi = pos_idx[cl * 8 + i];
    f16x8 vh = Ph[FRAG(m, mi >> 4, cbb) + (g * 16 + (mi & 15))];
    #pragma unroll
    for (int j = 0; j < 8; ++j)
      R[i][cbb * 32 + g * 8 + j] = (float)vh[j];
  }
  __syncthreads();
  {
    int d = t >> 2, q = t & 3, i = d >> 3, i2 = d & 7;
    const float4* Ri4 = (const float4*)(&R[i][q * 128]);
    const float4* Rj4 = (const float4*)(&R[i2][q * 128]);
    float p = 0.0f;
    #pragma unroll
    for (int c = 0; c < 32; ++c) {
      float4 a = Ri4[c], b = Rj4[c];
      p += a.x * b.x + a.y * b.y + a.z * b.z + a.w * b.w;
    }
    p += __shfl_down(p, 2, 4);
    p += __shfl_down(p, 1, 4);
    if (q == 0) D8[d] = p;
  }
  __syncthreads();
  if (t < 64) {
    int ii = t >> 3, jj = t & 7;
    float x2a = D8[ii * 8 + ii], x2b = D8[jj * 8 + jj];
    float z = x2a + x2b - 2.0f * D8[t];
    float dist = (z > 0.0f) ? sqrtf(z) : 0.0f;
    int mi = pos_idx[cl * 8 + ii];
    dap[((size_t)m * NN + mi) * KPOS + jj] = dist;
    if (ii == jj) x2[m * NN + mi] = x2a;
  }
}

// ---------------------------------------------------------------------------
// Kernel B v4: TRIANGLE tiling (Gram is symmetric). 10 tiles per m (4 diag +
// 6 off-diag) instead of 16; off-diag tiles run the epilogue in BOTH
// orientations (reusing the same dist); diag tiles stage only A (4KB/chunk).
// Structure otherwise = round-7's proven 2-phase global_load_lds pipeline.
// ---------------------------------------------------------------------------
#define MFMA16(d, a, b) d = __builtin_amdgcn_mfma_f32_16x16x32_f16(a, b, d, 0, 0, 0)

__global__ __launch_bounds__(256) void kB(
    const f16x8* __restrict__ Ph,
    const float* __restrict__ x2, const float* __restrict__ dap,
    const unsigned long long* __restrict__ neg_mask,
    float* __restrict__ s_acc, unsigned int* __restrict__ c_acc,
    unsigned int* __restrict__ done, float* __restrict__ out) {
  __shared__ __align__(16) char Lds[2][8 * 1024];   // 8 frag-KB x dbuf
  __shared__ float red_s[4];
  __shared__ unsigned int red_c[4];
  __shared__ unsigned int lastFlag;

  int bid = blockIdx.x;                 // 640 blocks
  int m = bid & 63;                     // XCD-aligned: m%8 == bid%8
  int sub = bid >> 6;                   // 0..9 triangle tile id
  int ti, tj;                           // A-side (rows/k) block i, B-side (cols/n) block j
  if (sub < 4) { ti = sub; tj = sub; }
  else {
    int u = sub - 4;                    // (0,1)(0,2)(0,3)(1,2)(1,3)(2,3)
    ti = (u < 3) ? 0 : ((u < 5) ? 1 : 2);
    tj = (u < 3) ? (u + 1) : ((u < 5) ? (u - 2) : 3);
  }
  const bool diag = (ti == tj);
  int t = threadIdx.x, lane = t & 63, w = t >> 6;
  int wr = w & 1, wc = w >> 1;          // wave: 32k x 32n sub-tile

  f32x4 hh[2][2];
  #pragma unroll
  for (int i = 0; i < 2; ++i)
    #pragma unroll
    for (int j = 0; j < 2; ++j) hh[i][j] = (f32x4){0.f, 0.f, 0.f, 0.f};

  // off-diag: 8 frag-blocks (b<4: A rows ti, b>=4: B rows tj); diag: 4 (A only)
  #define STAGE(nbuf, cbn)                                                   \
    if (diag) {                                                              \
      GLD_LDS16(Ph + FRAG(m, ti * 4 + w, (cbn)) + lane,                      \
                &Lds[nbuf][w * 1024]);                                       \
    } else {                                                                 \
      { int b = w * 2;     int rbg = (b < 4) ? (ti*4 + b) : (tj*4 + b - 4);  \
        GLD_LDS16(Ph + FRAG(m, rbg, (cbn)) + lane, &Lds[nbuf][b * 1024]); }  \
      { int b = w * 2 + 1; int rbg = (b < 4) ? (ti*4 + b) : (tj*4 + b - 4);  \
        GLD_LDS16(Ph + FRAG(m, rbg, (cbn)) + lane, &Lds[nbuf][b * 1024]); }  \
    }

  STAGE(0, 0);
  __syncthreads();
  #pragma unroll 1
  for (int cb = 0; cb < 16; ++cb) {
    int buf = cb & 1;
    if (cb < 15) STAGE(buf ^ 1, cb + 1);
    __builtin_amdgcn_sched_barrier(0);  // pin stage-issue before compute
    const f16x8* L  = (const f16x8*)(Lds[buf]);
    const f16x8* LB = diag ? L : (L + 4 * 64);
    f16x8 ah0 = L [(wr * 2 + 0) * 64 + lane];
    f16x8 ah1 = L [(wr * 2 + 1) * 64 + lane];
    f16x8 bh0 = LB[(wc * 2 + 0) * 64 + lane];
    f16x8 bh1 = LB[(wc * 2 + 1) * 64 + lane];
    MFMA16(hh[0][0], ah0, bh0); MFMA16(hh[0][1], ah0, bh1);
    MFMA16(hh[1][0], ah1, bh0); MFMA16(hh[1][1], ah1, bh1);
    __syncthreads();                    // drains vmcnt(0): buf^1 staged
  }

  // Epilogue. D frag: col = lane&15 (n side), row = (lane>>4)*4 + reg (k side).
  int col = lane & 15, rq = lane >> 4;
  int n0 = tj * 64 + wc * 32 + col;
  int n1 = n0 + 16;
  float x2n0 = x2[m * NN + n0], x2n1 = x2[m * NN + n1];
  float dv0[8], dv1[8];
  {
    const float4* dp0 = (const float4*)&dap[((size_t)m * NN + n0) * KPOS];
    const float4* dp1 = (const float4*)&dap[((size_t)m * NN + n1) * KPOS];
    float4 w0 = dp0[0], w1 = dp0[1], w2 = dp1[0], w3 = dp1[1];
    dv0[0]=w0.x; dv0[1]=w0.y; dv0[2]=w0.z; dv0[3]=w0.w;
    dv0[4]=w1.x; dv0[5]=w1.y; dv0[6]=w1.z; dv0[7]=w1.w;
    dv1[0]=w2.x; dv1[1]=w2.y; dv1[2]=w2.z; dv1[3]=w2.w;
    dv1[4]=w3.x; dv1[5]=w3.y; dv1[6]=w3.z; dv1[7]=w3.w;
  }
  unsigned long long nmw0 = neg_mask[n0 * 4 + ti];   // k word == ti
  unsigned long long nmw1 = neg_mask[n1 * 4 + ti];

  float ls = 0.0f; unsigned int lc = 0u;
  #pragma unroll
  for (int i = 0; i < 2; ++i) {
    #pragma unroll
    for (int reg = 0; reg < 4; ++reg) {
      int klo = wr * 32 + i * 16 + rq * 4 + reg;     // k & 63
      int k = ti * 64 + klo;
      float x2k = x2[m * NN + k];
      float z0 = x2n0 + x2k - 2.0f * hh[i][0][reg];
      float d0 = (z0 > 0.0f) ? sqrtf(z0) : 0.0f;
      float z1 = x2n1 + x2k - 2.0f * hh[i][1][reg];
      float d1 = (z1 > 0.0f) ? sqrtf(z1) : 0.0f;
      // orientation 1: n = cols (n0/n1), k = row
      if ((nmw0 >> klo) & 1ull) {
        #pragma unroll
        for (int p = 0; p < 8; ++p) {
          float tt = MARG + dv0[p] - d0;
          if (tt > 0.0f) { ls += tt; lc++; }
        }
      }
      if ((nmw1 >> klo) & 1ull) {
        #pragma unroll
        for (int p = 0; p < 8; ++p) {
          float tt = MARG + dv1[p] - d1;
          if (tt > 0.0f) { ls += tt; lc++; }
        }
      }
      // orientation 2 (off-diag only): n = row k, negatives = cols n0/n1
      if (!diag) {
        const float4* dpr = (const float4*)&dap[((size_t)m * NN + k) * KPOS];
        float4 q0 = dpr[0], q1 = dpr[1];
        unsigned long long nmr = neg_mask[k * 4 + tj];
        int bit0 = wc * 32 + col;
        if ((nmr >> bit0) & 1ull) {
          float tt;
          tt = MARG + q0.x - d0; if (tt > 0.0f) { ls += tt; lc++; }
          tt = MARG + q0.y - d0; if (tt > 0.0f) { ls += tt; lc++; }
          tt = MARG + q0.z - d0; if (tt > 0.0f) { ls += tt; lc++; }
          tt = MARG + q0.w - d0; if (tt > 0.0f) { ls += tt; lc++; }
          tt = MARG + q1.x - d0; if (tt > 0.0f) { ls += tt; lc++; }
          tt = MARG + q1.y - d0; if (tt > 0.0f) { ls += tt; lc++; }
          tt = MARG + q1.z - d0; if (tt > 0.0f) { ls += tt; lc++; }
          tt = MARG + q1.w - d0; if (tt > 0.0f) { ls += tt; lc++; }
        }
        if ((nmr >> (bit0 + 16)) & 1ull) {
          float tt;
          tt = MARG + q0.x - d1; if (tt > 0.0f) { ls += tt; lc++; }
          tt = MARG + q0.y - d1; if (tt > 0.0f) { ls += tt; lc++; }
          tt = MARG + q0.z - d1; if (tt > 0.0f) { ls += tt; lc++; }
          tt = MARG + q0.w - d1; if (tt > 0.0f) { ls += tt; lc++; }
          tt = MARG + q1.x - d1; if (tt > 0.0f) { ls += tt; lc++; }
          tt = MARG + q1.y - d1; if (tt > 0.0f) { ls += tt; lc++; }
          tt = MARG + q1.z - d1; if (tt > 0.0f) { ls += tt; lc++; }
          tt = MARG + q1.w - d1; if (tt > 0.0f) { ls += tt; lc++; }
        }
      }
    }
  }
  #pragma unroll
  for (int off = 32; off > 0; off >>= 1) {
    ls += __shfl_down(ls, off, 64);
    lc += __shfl_down(lc, off, 64);
  }
  if (lane == 0) { red_s[w] = ls; red_c[w] = lc; }
  __syncthreads();
  if (t == 0) {
    atomicAdd(&s_acc[m], red_s[0] + red_s[1] + red_s[2] + red_s[3]);
    atomicAdd(&c_acc[m], red_c[0] + red_c[1] + red_c[2] + red_c[3]);
    __threadfence();
    unsigned int prev = atomicAdd(done, 1u);
    lastFlag = (prev == 639u) ? 1u : 0u;
  }
  __syncthreads();
  if (lastFlag && t < 64) {             // last block finalizes (fold of kC)
    __threadfence();
    float c  = (float)c_acc[t];
    float sm = s_acc[t];
    float mean = (c > 0.0f) ? (sm / c) : 0.0f;
    float csum = c;
    #pragma unroll
    for (int off = 32; off > 0; off >>= 1) {
      mean += __shfl_down(mean, off, 64);
      csum += __shfl_down(csum, off, 64);
    }
    if (t == 0) {
      out[0] = mean / 64.0f;
      // lm.size = M * N * K * (N-K) = 64*256*8*248 = 32,505,856
      out[1] = (csum / 64.0f) / 32505856.0f;
    }
  }
}

extern "C" void kernel_launch(void* const* d_in, const int* in_sizes, int n_in,
                              void* d_out, int out_size, void* d_ws, size_t ws_size,
                              hipStream_t stream) {
  const float* feature = (const float*)d_in[0];
  const int*   label   = (const int*)d_in[1];
  char* w = (char*)d_ws;
  f16x8* Ph = (f16x8*)(w + PH_OFF);
  float* x2  = (float*)(w + X2_OFF);
  float* dap = (float*)(w + DAP_OFF);
  int*   pos = (int*)(w + POS_OFF);
  unsigned long long* neg = (unsigned long long*)(w + NEG_OFF);
  float* s_acc = (float*)(w + S_OFF);
  unsigned int* c_acc = (unsigned int*)(w + CNT_OFF);
  unsigned int* done  = (unsigned int*)(w + DONE_OFF);
  float* out = (float*)d_out;

  kTH<<<1025, 256, 0, stream>>>(feature, Ph, label, pos, neg, s_acc, c_acc, done);
  kA2<<<2048, 256, 0, stream>>>(Ph, pos, x2, dap);
  kB <<<640,  256, 0, stream>>>(Ph, x2, dap, neg, s_acc, c_acc, done, out);
}